// Round 4
// baseline (420.079 us; speedup 1.0000x reference)
//
#include <hip/hip_runtime.h>
#include <math.h>

// Problem constants (fixed shapes from setup_inputs)
#define B_N    16
#define T_LEN  65536
#define D_N    9                 // HARMONIC_NUM + 1
#define CHUNK  256
#define NCH    (T_LEN / CHUNK)   // 256 chunks per batch

#define RCP_SR (1.0f / 16000.0f)

#define AS1C(p) ((const __attribute__((address_space(1))) void*)(p))
#define AS3(p)  ((__attribute__((address_space(3))) void*)(p))

// ---------------------------------------------------------------------------
// Single fused kernel, PLAIN launch (cooperative API breaks under the
// harness's graph capture — R2). Grid-wide ordering is done with per-batch
// atomic counters instead; this is deadlock-free because the grid is
// exactly co-resident: 1024 blocks = 4/CU x 256 CU (LDS 36.9KB -> 4/CU,
// __launch_bounds__(256,4) caps VGPR at 128).
//
// Per WAVE (owns one (b,chunk); blocks never straddle batches):
//   1. issue f0 float4 load FIRST (vmcnt FIFO: scan waits vmcnt(9), not 0)
//   2. issue 9 coalesced 1KB noise->LDS (linear layout; readback at
//      (9*lane+q)*16B has bank pattern 4(l+q)%32 == linear b128 -> no
//      conflicts). Consumed LAST -> latency hidden under everything.
//   3. float intra-wave scan of rad_1; lane63 publishes frac(chunk total)
//      to csum[b][c], then release-fetch_add on ctr[b].
//   4. lane0 spin-polls ctr[b]==256 (acquire). vmcnt synergy: the poll's
//      atomic load retires behind the noise loads, and publishes happen
//      ~1us in vs ~5us noise arrival -> barrier is off the critical path.
//   5. read csum row (1KB, L2-hot), masked sum + butterfly -> exclusive
//      chunk prefix; per-timestep phase; 9-harmonic sin/noise dot; tanh.
// ---------------------------------------------------------------------------
__global__ __launch_bounds__(256, 4) void k_fused(const float* __restrict__ f0,
                                                  const float* __restrict__ noise,
                                                  const float* __restrict__ W,
                                                  const float* __restrict__ bias,
                                                  const float* __restrict__ rinit,
                                                  float* __restrict__ csum,
                                                  unsigned int* __restrict__ ctr,
                                                  float* __restrict__ out) {
    __shared__ float4 ldsbuf[4 * 576];      // 4 waves x 576 granules = 36864 B
    int tid  = threadIdx.x;
    int lane = tid & 63;
    int wid  = tid >> 6;
    int chunk = blockIdx.x * 4 + wid;
    int b = chunk >> 8;                     // 64 blocks per batch: no straddle
    int c = chunk & 255;
    int t = c * CHUNK + lane * 4;
    size_t bt = (size_t)b * T_LEN + t;

    // ---- 1. f0 load first (pre-barrier compute depends only on this).
    const float4 fv = *reinterpret_cast<const float4*>(f0 + bt);

    // uniform operands -> scalar loads (readfirstlane makes b provably uniform)
    int bu = __builtin_amdgcn_readfirstlane(b);
    const float* ri = rinit + bu * D_N;
    float wreg[D_N], rireg[D_N];
    #pragma unroll
    for (int h = 0; h < D_N; ++h) { wreg[h] = W[h]; rireg[h] = ri[h]; }
    float bb = bias[0];

    __builtin_amdgcn_sched_barrier(0);

    // ---- 2. noise -> LDS staging (9 x 1KB per wave), after f0.
    float4* ldsw = ldsbuf + wid * 576;
    const float* nbase = noise + ((size_t)b * T_LEN + (size_t)c * CHUNK) * D_N;
    #pragma unroll
    for (int q = 0; q < 9; ++q) {
        const float* g = nbase + (size_t)(lane + 64 * q) * 4;
        __builtin_amdgcn_global_load_lds(AS1C(g), AS3(ldsw + q * 64), 16, 0, 0);
    }
    __builtin_amdgcn_sched_barrier(0);

    // ---- 3. float intra-wave scan of fundamental phase increment.
    float f[4] = {fv.x, fv.y, fv.z, fv.w};
    float s[4];
    float run = 0.0f;
    #pragma unroll
    for (int j = 0; j < 4; ++j) {
        run += f[j] * RCP_SR;
        s[j] = run;
    }
    float incl = run;
    #pragma unroll
    for (int off = 1; off < 64; off <<= 1) {
        float n = __shfl_up(incl, off, 64);
        if (lane >= off) incl += n;
    }

    // publish chunk total: value store, then release add on the counter.
    if (lane == 63) {
        csum[(size_t)b * NCH + c] = __builtin_amdgcn_fractf(incl);
        __hip_atomic_fetch_add(ctr + b, 1u, __ATOMIC_RELEASE,
                               __HIP_MEMORY_SCOPE_AGENT);
    }

    // ---- 4. spin until all 256 chunks of this batch have published.
    // lane0 only; other lanes are exec-masked and reconverge after.
    if (lane == 0) {
        while (__hip_atomic_load(ctr + b, __ATOMIC_ACQUIRE,
                                 __HIP_MEMORY_SCOPE_AGENT) < 256u) {
            __builtin_amdgcn_s_sleep(8);
        }
    }
    __threadfence();   // wave-wide acquire: csum row reads see all publishes

    // ---- 5. exclusive chunk prefix: lane l holds csum[b][4l..4l+3],
    // mask by global idx < c, butterfly-sum (float, magnitude <= 256).
    const float4 cs4 = *reinterpret_cast<const float4*>(csum + (size_t)b * NCH + lane * 4);
    int e0 = lane * 4;
    float pre = (e0 + 0 < c ? cs4.x : 0.0f)
              + (e0 + 1 < c ? cs4.y : 0.0f)
              + (e0 + 2 < c ? cs4.z : 0.0f)
              + (e0 + 3 < c ? cs4.w : 0.0f);
    #pragma unroll
    for (int off = 32; off >= 1; off >>= 1)
        pre += __shfl_xor(pre, off, 64);

    float base = __builtin_amdgcn_fractf(pre) + (incl - run);

    // per-timestep fundamental phase in [0,1), uv gates, noise amps.
    float fr[4], uvf[4], na[4];
    #pragma unroll
    for (int j = 0; j < 4; ++j) {
        fr[j] = __builtin_amdgcn_fractf(base + s[j]);   // base+s[j] <= ~8
        bool uv = f[j] > 0.0f;
        uvf[j] = uv ? 0.1f : 0.0f;                   // fold SINE_AMP into uv
        na[j]  = uv ? 0.003f : (float)(0.1 / 3.0);   // NOISE_STD : SINE_AMP/3
    }

    // ---- wait for noise staging (wave-private LDS region: no barrier).
    asm volatile("s_waitcnt vmcnt(0)" ::: "memory");

    // per-lane readback: granule (9*lane+q); bank pattern == linear b128.
    float nz[36];
    #pragma unroll
    for (int q = 0; q < 9; ++q) {
        float4 v4 = ldsw[9 * lane + q];
        nz[4 * q + 0] = v4.x; nz[4 * q + 1] = v4.y;
        nz[4 * q + 2] = v4.z; nz[4 * q + 3] = v4.w;
    }

    float acc[4] = {0.f, 0.f, 0.f, 0.f};
    #pragma unroll
    for (int h = 0; h < D_N; ++h) {
        const float hf = (float)(h + 1);
        const float wh = wreg[h];
        const float rih = rireg[h];
        #pragma unroll
        for (int j = 0; j < 4; ++j) {
            float x  = fmaf(fr[j], hf, rih);               // phase*h + init
            float xf = __builtin_amdgcn_fractf(x);         // frac -> [0,1)
            float sn = __builtin_amdgcn_sinf(xf);          // sin(2*pi*xf)
            float sw = fmaf(na[j], nz[j * 9 + h], sn * uvf[j]);
            acc[j] = fmaf(sw, wh, acc[j]);
        }
    }

    // tanh(x) = 1 - 2/(exp(2x)+1)
    float4 o;
    #pragma unroll
    for (int j = 0; j < 4; ++j) {
        float y = acc[j] + bb;
        float e = __expf(2.0f * y);
        float r = __builtin_amdgcn_rcpf(e + 1.0f);
        float th = 1.0f - 2.0f * r;
        (&o.x)[j] = th;
    }
    *reinterpret_cast<float4*>(out + bt) = o;
}

// ---------------------------------------------------------------------------
extern "C" void kernel_launch(void* const* d_in, const int* in_sizes, int n_in,
                              void* d_out, int out_size, void* d_ws, size_t ws_size,
                              hipStream_t stream) {
    const float* f0    = (const float*)d_in[0];
    const float* rinit = (const float*)d_in[1];
    const float* noise = (const float*)d_in[2];
    const float* W     = (const float*)d_in[3];
    const float* bias  = (const float*)d_in[4];
    float* out = (float*)d_out;

    // workspace layout: csum [16*256] f32, then ctr [16] u32
    float* csum = (float*)d_ws;
    unsigned int* ctr = (unsigned int*)(csum + (size_t)B_N * NCH);

    // zero the 16 per-batch counters each replay (graph-capturable).
    hipMemsetAsync(ctr, 0, B_N * sizeof(unsigned int), stream);

    k_fused<<<(B_N * NCH) / 4, 256, 0, stream>>>(f0, noise, W, bias, rinit,
                                                 csum, ctr, out);
}

// Round 5
// 35.023 us; speedup vs baseline: 11.9943x; 11.9943x over previous
//
#include <hip/hip_runtime.h>
#include <math.h>

// Problem constants (fixed shapes from setup_inputs)
#define B_N    16
#define T_LEN  65536
#define D_N    9                 // HARMONIC_NUM + 1
#define CHUNK  256
#define NCH    (T_LEN / CHUNK)   // 256 chunks per batch

#define RCP_SR (1.0f / 16000.0f)

#define AS1C(p) ((const __attribute__((address_space(1))) void*)(p))
#define AS3(p)  ((__attribute__((address_space(3))) void*)(p))

// ---------------------------------------------------------------------------
// Single fused kernel, PLAIN launch. Cross-block sync via VALUE-CARRYING
// flags, not acquire/release: csum[] is pre-set to qNaN (memset 0xFF); each
// wave publishes frac(chunk_total) with ONE relaxed agent atomic store
// (write-through to the coherent LLC, no wbl2); pollers use relaxed agent
// atomic loads (LLC-bypassing, NO buffer_inv). R4's 420us disaster was the
// acquire/release cache-maintenance storm (per-poll L2 invalidate + per-wave
// L2 writeback on non-coherent XCD L2s); with value-flags there is nothing
// to order, so no fences exist at all.
//
// Deadlock-free: grid exactly co-resident (1024 blocks = 4/CU x 256 CU;
// LDS 36.9KB -> 4 blocks/CU; launch_bounds caps VGPR at 128, measured 52;
// R4 measured occupancy ~45% ~= the 50% structural cap, proving residency).
// Poll loop is bounded so a wrong assumption fails absmax, not hangs.
//
// Per WAVE (owns one (b,chunk)):
//   1. f0 float4 load issued FIRST (vmcnt FIFO: scan waits vmcnt(9), noise
//      stays in flight).
//   2. 9 coalesced 1KB noise->LDS stages (linear layout; readback at
//      (9*lane+q)*16B has bank pattern 4(l+q)%32 == linear b128 -> no
//      conflicts). Consumed LAST.
//   3. float intra-wave scan; lane63 publishes frac(total) (relaxed store).
//   4. poll own 4 csum entries until non-NaN (wave ballot). First poll's
//      value-wait retires behind the noise loads (~6us), publishes landed
//      at ~1.5us -> expected iterations ~1, barrier off the critical path.
//   5. masked butterfly -> exclusive chunk prefix; phase; 9-harmonic
//      sin/noise dot; tanh; float4 store.
// ---------------------------------------------------------------------------
__global__ __launch_bounds__(256, 4) void k_fused(const float* __restrict__ f0,
                                                  const float* __restrict__ noise,
                                                  const float* __restrict__ W,
                                                  const float* __restrict__ bias,
                                                  const float* __restrict__ rinit,
                                                  float* __restrict__ csum,
                                                  float* __restrict__ out) {
    __shared__ float4 ldsbuf[4 * 576];      // 4 waves x 576 granules = 36864 B
    int tid  = threadIdx.x;
    int lane = tid & 63;
    int wid  = tid >> 6;
    int chunk = blockIdx.x * 4 + wid;
    int b = chunk >> 8;                     // 64 blocks per batch: no straddle
    int c = chunk & 255;
    int t = c * CHUNK + lane * 4;
    size_t bt = (size_t)b * T_LEN + t;

    // ---- 1. f0 load first (pre-barrier compute depends only on this).
    const float4 fv = *reinterpret_cast<const float4*>(f0 + bt);

    // uniform operands -> scalar loads (readfirstlane makes b provably uniform)
    int bu = __builtin_amdgcn_readfirstlane(b);
    const float* ri = rinit + bu * D_N;
    float wreg[D_N], rireg[D_N];
    #pragma unroll
    for (int h = 0; h < D_N; ++h) { wreg[h] = W[h]; rireg[h] = ri[h]; }
    float bb = bias[0];

    __builtin_amdgcn_sched_barrier(0);

    // ---- 2. noise -> LDS staging (9 x 1KB per wave), after f0.
    float4* ldsw = ldsbuf + wid * 576;
    const float* nbase = noise + ((size_t)b * T_LEN + (size_t)c * CHUNK) * D_N;
    #pragma unroll
    for (int q = 0; q < 9; ++q) {
        const float* g = nbase + (size_t)(lane + 64 * q) * 4;
        __builtin_amdgcn_global_load_lds(AS1C(g), AS3(ldsw + q * 64), 16, 0, 0);
    }
    __builtin_amdgcn_sched_barrier(0);

    // ---- 3. float intra-wave scan of fundamental phase increment.
    float f[4] = {fv.x, fv.y, fv.z, fv.w};
    float s[4];
    float run = 0.0f;
    #pragma unroll
    for (int j = 0; j < 4; ++j) {
        run += f[j] * RCP_SR;
        s[j] = run;
    }
    float incl = run;
    #pragma unroll
    for (int off = 1; off < 64; off <<= 1) {
        float n = __shfl_up(incl, off, 64);
        if (lane >= off) incl += n;
    }

    // publish chunk total: single relaxed agent store (value IS the flag;
    // frac() is always in [0,1), never NaN). No waitcnt, no fence.
    if (lane == 63) {
        __hip_atomic_store(csum + (size_t)b * NCH + c,
                           __builtin_amdgcn_fractf(incl),
                           __ATOMIC_RELAXED, __HIP_MEMORY_SCOPE_AGENT);
    }

    // ---- 4. poll own 4 entries until published (NaN = not yet).
    // Relaxed agent loads read the coherent LLC; no cache maintenance.
    const float* cp = csum + (size_t)b * NCH + lane * 4;
    float c0, c1, c2, c3;
    for (int it = 0; it < (1 << 20); ++it) {
        c0 = __hip_atomic_load(cp + 0, __ATOMIC_RELAXED, __HIP_MEMORY_SCOPE_AGENT);
        c1 = __hip_atomic_load(cp + 1, __ATOMIC_RELAXED, __HIP_MEMORY_SCOPE_AGENT);
        c2 = __hip_atomic_load(cp + 2, __ATOMIC_RELAXED, __HIP_MEMORY_SCOPE_AGENT);
        c3 = __hip_atomic_load(cp + 3, __ATOMIC_RELAXED, __HIP_MEMORY_SCOPE_AGENT);
        bool bad = __builtin_isnan(c0) || __builtin_isnan(c1)
                || __builtin_isnan(c2) || __builtin_isnan(c3);
        if (!__any(bad)) break;
        __builtin_amdgcn_s_sleep(1);
    }

    // ---- 5. exclusive chunk prefix: lane l holds csum[b][4l..4l+3],
    // mask by global idx < c, butterfly-sum (float, magnitude <= 256).
    int e0 = lane * 4;
    float pre = (e0 + 0 < c ? c0 : 0.0f)
              + (e0 + 1 < c ? c1 : 0.0f)
              + (e0 + 2 < c ? c2 : 0.0f)
              + (e0 + 3 < c ? c3 : 0.0f);
    #pragma unroll
    for (int off = 32; off >= 1; off >>= 1)
        pre += __shfl_xor(pre, off, 64);

    float base = __builtin_amdgcn_fractf(pre) + (incl - run);

    // per-timestep fundamental phase in [0,1), uv gates, noise amps.
    float fr[4], uvf[4], na[4];
    #pragma unroll
    for (int j = 0; j < 4; ++j) {
        fr[j] = __builtin_amdgcn_fractf(base + s[j]);   // base+s[j] <= ~8
        bool uv = f[j] > 0.0f;
        uvf[j] = uv ? 0.1f : 0.0f;                   // fold SINE_AMP into uv
        na[j]  = uv ? 0.003f : (float)(0.1 / 3.0);   // NOISE_STD : SINE_AMP/3
    }

    // ---- wait for noise staging (wave-private LDS region: no barrier).
    asm volatile("s_waitcnt vmcnt(0)" ::: "memory");

    // per-lane readback: granule (9*lane+q); bank pattern == linear b128.
    float nz[36];
    #pragma unroll
    for (int q = 0; q < 9; ++q) {
        float4 v4 = ldsw[9 * lane + q];
        nz[4 * q + 0] = v4.x; nz[4 * q + 1] = v4.y;
        nz[4 * q + 2] = v4.z; nz[4 * q + 3] = v4.w;
    }

    float acc[4] = {0.f, 0.f, 0.f, 0.f};
    #pragma unroll
    for (int h = 0; h < D_N; ++h) {
        const float hf = (float)(h + 1);
        const float wh = wreg[h];
        const float rih = rireg[h];
        #pragma unroll
        for (int j = 0; j < 4; ++j) {
            float x  = fmaf(fr[j], hf, rih);               // phase*h + init
            float xf = __builtin_amdgcn_fractf(x);         // frac -> [0,1)
            float sn = __builtin_amdgcn_sinf(xf);          // sin(2*pi*xf)
            float sw = fmaf(na[j], nz[j * 9 + h], sn * uvf[j]);
            acc[j] = fmaf(sw, wh, acc[j]);
        }
    }

    // tanh(x) = 1 - 2/(exp(2x)+1)
    float4 o;
    #pragma unroll
    for (int j = 0; j < 4; ++j) {
        float y = acc[j] + bb;
        float e = __expf(2.0f * y);
        float r = __builtin_amdgcn_rcpf(e + 1.0f);
        float th = 1.0f - 2.0f * r;
        (&o.x)[j] = th;
    }
    *reinterpret_cast<float4*>(out + bt) = o;
}

// ---------------------------------------------------------------------------
extern "C" void kernel_launch(void* const* d_in, const int* in_sizes, int n_in,
                              void* d_out, int out_size, void* d_ws, size_t ws_size,
                              hipStream_t stream) {
    const float* f0    = (const float*)d_in[0];
    const float* rinit = (const float*)d_in[1];
    const float* noise = (const float*)d_in[2];
    const float* W     = (const float*)d_in[3];
    const float* bias  = (const float*)d_in[4];
    float* out = (float*)d_out;

    // workspace: csum [16*256] f32, pre-set to qNaN (0xFF bytes) each replay
    float* csum = (float*)d_ws;
    hipMemsetAsync(csum, 0xFF, (size_t)B_N * NCH * sizeof(float), stream);

    k_fused<<<(B_N * NCH) / 4, 256, 0, stream>>>(f0, noise, W, bias, rinit,
                                                 csum, out);
}

// Round 6
// 17.896 us; speedup vs baseline: 23.4729x; 1.9570x over previous
//
#include <hip/hip_runtime.h>
#include <math.h>

// Problem constants (fixed shapes from setup_inputs)
#define B_N    16
#define T_LEN  65536
#define D_N    9                 // HARMONIC_NUM + 1
#define CHUNK  256
#define NCH    (T_LEN / CHUNK)   // 256 chunks per batch

#define RCP_SR (1.0f / 16000.0f)

#define AS1C(p) ((const __attribute__((address_space(1))) void*)(p))
#define AS3(p)  ((__attribute__((address_space(3))) void*)(p))

// ---------------------------------------------------------------------------
// Pass 1: per-(b,chunk) sum of rad_1 = f0 * (1/16000), double accumulate,
// stored as float frac. Only harmonic 1 is scanned; others are derived as
// integer multiples (frac-preserving).
// grid = 1024 blocks x 256 threads; each WAVE owns one chunk (4 t/lane).
// ---------------------------------------------------------------------------
__global__ __launch_bounds__(256) void k_chunksum(const float* __restrict__ f0,
                                                  float* __restrict__ csum) {
    int tid  = threadIdx.x;
    int lane = tid & 63;
    int wid  = tid >> 6;
    int chunk = blockIdx.x * 4 + wid;       // 0..4095 global chunk id
    int b = chunk >> 8;
    int c = chunk & 255;
    int t = c * CHUNK + lane * 4;
    size_t bt = (size_t)b * T_LEN + t;

    const float4 fv = *reinterpret_cast<const float4*>(f0 + bt);
    double s = (double)(fv.x * RCP_SR) + (double)(fv.y * RCP_SR)
             + (double)(fv.z * RCP_SR) + (double)(fv.w * RCP_SR);

    #pragma unroll
    for (int off = 32; off >= 1; off >>= 1)
        s += __shfl_down(s, off, 64);

    if (lane == 0) {
        double fr = s - floor(s);
        csum[(size_t)b * NCH + c] = (float)fr;
    }
}

// ---------------------------------------------------------------------------
// Pass 2 (main). Each WAVE owns one (b,chunk); lane owns 4 timesteps.
//
// RESTRUCTURE vs R3: the output factors as
//     out[j] = tanh( uvf[j]*B[j] + na[j]*D[j] + bias )
//   B[j] = sum_h sin(2pi*frac(fr[j]*h + ri_h)) * W_h     (noise-INdependent)
//   D[j] = sum_h W_h * noise[j][h]                        (noise-dependent)
// All 36 sins + the B accumulation run BEFORE the noise wait (hidden under
// the ~6us HBM stream); the post-wait work collapses to 9 ds_read_b128 +
// 36 fmaf + tanh (~250 cyc vs ~1000+ before). Noise granules are consumed
// with a vmcnt STAIRCASE (granule q only needs vmcnt(8-q); issue order is
// f0, csum, n0..n8 so FIFO retire makes that exact) instead of one
// vmcnt(0) drain -- the dot product starts when the FIRST KB lands.
// grid = 1024 blocks x 256 threads; LDS 36.9KB/block -> 4 blocks/CU.
// ---------------------------------------------------------------------------
#define WAITV(n) asm volatile("s_waitcnt vmcnt(" #n ")" ::: "memory")

// consume granule Q: 4 floats, flat noise index 4Q+i -> (j=(4Q+i)/9, h=(4Q+i)%9)
#define CONS(Q) do {                                                        \
    float4 v4 = ldsw[9 * lane + (Q)];                                       \
    dacc[(4*(Q)+0)/9] = fmaf(wreg[(4*(Q)+0)%9], v4.x, dacc[(4*(Q)+0)/9]);   \
    dacc[(4*(Q)+1)/9] = fmaf(wreg[(4*(Q)+1)%9], v4.y, dacc[(4*(Q)+1)/9]);   \
    dacc[(4*(Q)+2)/9] = fmaf(wreg[(4*(Q)+2)%9], v4.z, dacc[(4*(Q)+2)/9]);   \
    dacc[(4*(Q)+3)/9] = fmaf(wreg[(4*(Q)+3)%9], v4.w, dacc[(4*(Q)+3)/9]);   \
} while (0)

__global__ __launch_bounds__(256, 4) void k_main(const float* __restrict__ f0,
                                                 const float* __restrict__ noise,
                                                 const float* __restrict__ W,
                                                 const float* __restrict__ bias,
                                                 const float* __restrict__ rinit,
                                                 const float* __restrict__ csum,
                                                 float* __restrict__ out) {
    __shared__ float4 ldsbuf[4 * 576];      // 4 waves x 576 granules = 36864 B
    int tid  = threadIdx.x;
    int lane = tid & 63;
    int wid  = tid >> 6;
    int chunk = blockIdx.x * 4 + wid;
    int b = chunk >> 8;
    int c = chunk & 255;
    int t = c * CHUNK + lane * 4;
    size_t bt = (size_t)b * T_LEN + t;

    // ---- issue the loads the PRE-WAIT compute depends on FIRST
    // (vmcnt FIFO: these retire before the 9 noise stages).
    const float4 fv  = *reinterpret_cast<const float4*>(f0 + bt);
    const float4 cs4 = *reinterpret_cast<const float4*>(csum + (size_t)b * NCH + lane * 4);

    // uniform operands -> scalar loads (readfirstlane makes b provably uniform)
    int bu = __builtin_amdgcn_readfirstlane(b);
    const float* ri = rinit + bu * D_N;
    float wreg[D_N], rireg[D_N];
    #pragma unroll
    for (int h = 0; h < D_N; ++h) { wreg[h] = W[h]; rireg[h] = ri[h]; }
    float bb = bias[0];

    __builtin_amdgcn_sched_barrier(0);

    // ---- noise -> LDS staging (9 x 1KB per wave), issued AFTER f0/csum.
    // Linear layout; per-lane readback granule (9*lane+q): measured 0 bank
    // conflicts (R4/R5 rocprof).
    float4* ldsw = ldsbuf + wid * 576;
    const float* nbase = noise + ((size_t)b * T_LEN + (size_t)c * CHUNK) * D_N;
    #pragma unroll
    for (int q = 0; q < 9; ++q) {
        const float* g = nbase + (size_t)(lane + 64 * q) * 4;
        __builtin_amdgcn_global_load_lds(AS1C(g), AS3(ldsw + q * 64), 16, 0, 0);
    }
    __builtin_amdgcn_sched_barrier(0);

    // ---- float intra-wave scan of fundamental phase increment.
    float f[4] = {fv.x, fv.y, fv.z, fv.w};
    float s[4];
    float run = 0.0f;
    #pragma unroll
    for (int j = 0; j < 4; ++j) {
        run += f[j] * RCP_SR;
        s[j] = run;
    }
    float incl = run;
    #pragma unroll
    for (int off = 1; off < 64; off <<= 1) {
        float n = __shfl_up(incl, off, 64);
        if (lane >= off) incl += n;
    }

    // ---- exclusive chunk prefix: lane l holds csum[b][4l..4l+3],
    // mask by global idx < c, butterfly-sum (float, magnitude <= 256).
    int e0 = lane * 4;
    float pre = (e0 + 0 < c ? cs4.x : 0.0f)
              + (e0 + 1 < c ? cs4.y : 0.0f)
              + (e0 + 2 < c ? cs4.z : 0.0f)
              + (e0 + 3 < c ? cs4.w : 0.0f);
    #pragma unroll
    for (int off = 32; off >= 1; off >>= 1)
        pre += __shfl_xor(pre, off, 64);

    float base = __builtin_amdgcn_fractf(pre) + (incl - run);

    // per-timestep fundamental phase in [0,1), uv gates, noise amps.
    float fr[4], uvf[4], na[4];
    #pragma unroll
    for (int j = 0; j < 4; ++j) {
        fr[j] = __builtin_amdgcn_fractf(base + s[j]);   // base+s[j] <= ~8
        bool uv = f[j] > 0.0f;
        uvf[j] = uv ? 0.1f : 0.0f;                   // fold SINE_AMP into uv
        na[j]  = uv ? 0.003f : (float)(0.1 / 3.0);   // NOISE_STD : SINE_AMP/3
    }

    // ---- noise-INdependent harmonic sum B[j], fully under the load shadow.
    float B[4] = {0.f, 0.f, 0.f, 0.f};
    #pragma unroll
    for (int h = 0; h < D_N; ++h) {
        const float hf = (float)(h + 1);
        const float wh = wreg[h];
        const float rih = rireg[h];
        #pragma unroll
        for (int j = 0; j < 4; ++j) {
            float x  = fmaf(fr[j], hf, rih);               // phase*h + init
            float xf = __builtin_amdgcn_fractf(x);         // frac -> [0,1)
            float sn = __builtin_amdgcn_sinf(xf);          // sin(2*pi*xf)
            B[j] = fmaf(sn, wh, B[j]);
        }
    }

    // ---- noise-dependent dot D[j], vmcnt staircase per granule.
    float dacc[4] = {0.f, 0.f, 0.f, 0.f};
    WAITV(8); CONS(0);
    WAITV(7); CONS(1);
    WAITV(6); CONS(2);
    WAITV(5); CONS(3);
    WAITV(4); CONS(4);
    WAITV(3); CONS(5);
    WAITV(2); CONS(6);
    WAITV(1); CONS(7);
    WAITV(0); CONS(8);

    // ---- epilogue: y = uvf*B + na*D + bias; tanh = 1 - 2/(exp(2y)+1)
    float4 o;
    #pragma unroll
    for (int j = 0; j < 4; ++j) {
        float y = fmaf(na[j], dacc[j], fmaf(uvf[j], B[j], bb));
        float e = __expf(2.0f * y);
        float r = __builtin_amdgcn_rcpf(e + 1.0f);
        float th = 1.0f - 2.0f * r;
        (&o.x)[j] = th;
    }
    *reinterpret_cast<float4*>(out + bt) = o;
}

// ---------------------------------------------------------------------------
extern "C" void kernel_launch(void* const* d_in, const int* in_sizes, int n_in,
                              void* d_out, int out_size, void* d_ws, size_t ws_size,
                              hipStream_t stream) {
    const float* f0    = (const float*)d_in[0];
    const float* rinit = (const float*)d_in[1];
    const float* noise = (const float*)d_in[2];
    const float* W     = (const float*)d_in[3];
    const float* bias  = (const float*)d_in[4];
    float* out = (float*)d_out;

    // workspace: csum [16*256] f32
    float* csum = (float*)d_ws;

    k_chunksum<<<(B_N * NCH) / 4, 256, 0, stream>>>(f0, csum);
    k_main<<<(B_N * NCH) / 4, 256, 0, stream>>>(f0, noise, W, bias, rinit, csum, out);
}